// Round 11
// baseline (181.731 us; speedup 1.0000x reference)
//
#include <hip/hip_runtime.h>
#include <hip/hip_bf16.h>

typedef __attribute__((ext_vector_type(8))) short short8;
typedef __attribute__((ext_vector_type(4))) float f32x4;
typedef __attribute__((ext_vector_type(16))) float f32x16;

#define WS_B0_OFFSET  18874368u   // b0 after Wt2 (9*1024*1024 bf16)

// -------- Phase 0a: W[d][i][o] fp32 -> Wt2[(d*128+q)][o][j] bf16 (i = q*8+j) --------
__global__ void wt2_kernel(const float* __restrict__ W, short* __restrict__ Wt2) {
    int bid = blockIdx.x;            // 0..1151
    int d = bid >> 7, q = bid & 127;
    int t = threadIdx.x;             // 256
    const float* src = W + (size_t)d * 1048576 + (size_t)q * 8 * 1024;
    short* dst = Wt2 + ((size_t)(d * 128 + q) << 13);
#pragma unroll
    for (int u = 0; u < 4; u++) {
        int o = u * 256 + t;
        short8 v;
#pragma unroll
        for (int j = 0; j < 8; j++)
            v[j] = (short)__bfloat16_as_ushort(__float2bfloat16(src[(size_t)j * 1024 + o]));
        *(short8*)(dst + (size_t)o * 8) = v;
    }
}

// -------- Phase 0b: b0[o] = sum_i W[0][i][o], two-stage --------
__global__ void colsum1(const float* __restrict__ W, float* __restrict__ part) {
    int s = blockIdx.x >> 2;
    int o = (blockIdx.x & 3) * 256 + threadIdx.x;
    const float* p = W + (size_t)s * 32 * 1024 + o;
    float acc = 0.f;
#pragma unroll
    for (int i = 0; i < 32; i++) acc += p[(size_t)i * 1024];
    part[s * 1024 + o] = acc;
}
__global__ void colsum2(const float* __restrict__ part, float* __restrict__ b0) {
    int o = blockIdx.x * 256 + threadIdx.x;
    float acc = 0.f;
#pragma unroll
    for (int s = 0; s < 32; s++) acc += part[s * 1024 + o];
    b0[o] = acc;
}

__device__ __forceinline__ float fast_tanh(float t) {
    float e = __expf(t + t);
    return 1.0f - 2.0f * __builtin_amdgcn_rcpf(e + 1.0f);
}

// -------- Phase 1: fused tanh + Chebyshev + GEMM, zero-LDS zero-barrier loop ----
// 512 thr = 8 waves = wr(2) x wc(2) x kh(2). Tile 128x256, BK=32, grid 256.
// Wave = 64 rows x 128 cols x 16k. Thread owns A rows wr*64+m*32+(lane&31),
// k-chunk kh*16+(lane>>5)*8 == exactly the mfma_32x32x16 A-fragment: the
// recurrence state IS the A operand (A never touches LDS; recurrence dup = 2).
// B: 4 x global_load_dwordx4 / wave / step from the XCD-pinned L2 panel,
// ping-ponged ONE DEGREE AHEAD (no same-step load-use). No barriers in loop.
// kh-split accumulators merged via LDS once at the end (4 chunks).
extern "C" __global__ void __launch_bounds__(512, 2)
cheby_gemm(const float* __restrict__ x, const short* __restrict__ Wt2,
           const float* __restrict__ b0v, const float* __restrict__ scp,
           const float* __restrict__ bip, float* __restrict__ out) {
    __shared__ __align__(16) char lds[32768];   // epilogue merge only

    const int tid = threadIdx.x, lane = tid & 63, wid = tid >> 6;
    const int wc = wid & 1, wr = (wid >> 1) & 1, kh = wid >> 2;
    const int tn = blockIdx.x & 3, tm = blockIdx.x >> 2;  // bid&7=XCD -> fixed tn
    const int m0 = tm << 7, n0 = tn << 8;
    const float sc = scp[0], bi = bip[0];
    const char* wtb = (const char*)Wt2;

    // x pointer for this thread's 2 owned rows x 8 k-elems
    const float* xptr = x + (size_t)(m0 + wr * 64 + (lane & 31)) * 1024
                          + kh * 16 + ((lane >> 5) << 3);

    // B fragment byte offsets (4 n-blocks); chunk c = kh*2 + (lane>>5)
    const int c = kh * 2 + (lane >> 5);
    int bofs[4];
#pragma unroll
    for (int n = 0; n < 4; n++)
        bofs[n] = (c << 14) + ((n0 + wc * 128 + n * 32 + (lane & 31)) << 4);

    auto bld = [&](short8* bf, int dd, int icc) {
        const char* p = wtb + ((size_t)(dd * 128 + icc * 4) << 14);
#pragma unroll
        for (int n = 0; n < 4; n++)
            bf[n] = *(const short8*)(p + bofs[n]);
    };

    f32x4 xv[2][2];
    auto loadx = [&](int icc) {
#pragma unroll
        for (int m = 0; m < 2; m++) {
            const float* p = xptr + (size_t)(m << 5) * 1024 + (icc << 5);
            xv[m][0] = *(const f32x4*)p;
            xv[m][1] = *(const f32x4*)(p + 4);
        }
    };

    float x2[16], tA[16], tB[16];
    auto dotanh = [&]() {
#pragma unroll
        for (int m = 0; m < 2; m++)
#pragma unroll
            for (int j = 0; j < 4; j++) {
                float a = fast_tanh(fmaf(xv[m][0][j], sc, bi));
                float b = fast_tanh(fmaf(xv[m][1][j], sc, bi));
                tA[m * 8 + j]     = a;  x2[m * 8 + j]     = a + a;
                tA[m * 8 + 4 + j] = b;  x2[m * 8 + 4 + j] = b + b;
            }
    };

    auto cvt8 = [](const float* t) -> short8 {
        short8 r;
#pragma unroll
        for (int j = 0; j < 8; j++)
            r[j] = (short)__bfloat16_as_ushort(__float2bfloat16(t[j]));
        return r;
    };

    f32x16 acc[2][4];
#pragma unroll
    for (int n = 0; n < 4; n++) {
        float v = (kh == 0) ? b0v[n0 + wc * 128 + n * 32 + (lane & 31)] : 0.0f;
        f32x16 a;
#pragma unroll
        for (int r = 0; r < 16; r++) a[r] = v;
        acc[0][n] = a;
        acc[1][n] = a;
    }

    short8 afA[2], afB[2], bfA[4], bfB[4];
    auto burst = [&](const short8* af, const short8* bf) {
        __builtin_amdgcn_s_setprio(1);
#pragma unroll
        for (int m = 0; m < 2; m++)
#pragma unroll
            for (int n = 0; n < 4; n++)
                acc[m][n] = __builtin_amdgcn_mfma_f32_32x32x16_bf16(af[m], bf[n], acc[m][n], 0, 0, 0);
        __builtin_amdgcn_s_setprio(0);
    };

    // ---- prologue: x(0) -> T1 in regs; B(d=1, ic=0) -> bfA ----
    loadx(0);
    bld(bfA, 1, 0);
    dotanh();
    afA[0] = cvt8(tA); afA[1] = cvt8(tA + 8);

    for (int ic = 0; ic < 32; ++ic) {
        const int icn = ic < 31 ? ic + 1 : 31;
        { // s0 (d=1): make T2
            bld(bfB, 2, ic);
#pragma unroll
            for (int j = 0; j < 16; j++) tB[j] = fmaf(x2[j], tA[j], -1.0f);
            afB[0] = cvt8(tB); afB[1] = cvt8(tB + 8);
            burst(afA, bfA);
        }
        { // s1 (d=2): make T3
            bld(bfA, 3, ic);
#pragma unroll
            for (int j = 0; j < 16; j++) tA[j] = fmaf(x2[j], tB[j], -tA[j]);
            afA[0] = cvt8(tA); afA[1] = cvt8(tA + 8);
            burst(afB, bfB);
        }
#define RSTEP(D, DST, SRC, AFN, AFU, BFL, BFU, XPRE)              \
        {                                                         \
            bld(BFL, D, ic);                                      \
            if (XPRE) loadx(icn);                                 \
_Pragma("unroll")                                                 \
            for (int j = 0; j < 16; j++)                          \
                DST[j] = fmaf(x2[j], SRC[j], -DST[j]);            \
            AFN[0] = cvt8(DST); AFN[1] = cvt8(DST + 8);           \
            burst(AFU, BFU);                                      \
        }
        RSTEP(4, tB, tA, afB, afA, bfB, bfA, 0)   // s2: d=3, make T4
        RSTEP(5, tA, tB, afA, afB, bfA, bfB, 0)   // s3: d=4, make T5
        RSTEP(6, tB, tA, afB, afA, bfB, bfA, 1)   // s4: d=5, make T6; prefetch x'
        RSTEP(7, tA, tB, afA, afB, bfA, bfB, 0)   // s5: d=6, make T7
        RSTEP(8, tB, tA, afB, afA, bfB, bfA, 0)   // s6: d=7, make T8
#undef RSTEP
        { // s7 (d=8): burst T8; load B(d=1, ic+1); tanh(x') -> T1'
            bld(bfA, 1, icn);
            dotanh();
            afA[0] = cvt8(tA); afA[1] = cvt8(tA + 8);
            burst(afB, bfB);
        }
    }

    // -------- kh-split merge via LDS, 4 chunks (m x n-half) --------
#pragma unroll
    for (int m = 0; m < 2; m++)
#pragma unroll
        for (int nh = 0; nh < 2; nh++) {
            if (kh == 1) {
#pragma unroll
                for (int nn = 0; nn < 2; nn++) {
                    int n = nh * 2 + nn;
                    char* base = lds + (((wr * 2 + wc) * 2 + nn) << 12) + lane * 64;
#pragma unroll
                    for (int q = 0; q < 4; q++) {
                        f32x4 v = {acc[m][n][q * 4 + 0], acc[m][n][q * 4 + 1],
                                   acc[m][n][q * 4 + 2], acc[m][n][q * 4 + 3]};
                        *(f32x4*)(base + ((q ^ (lane & 3)) << 4)) = v;
                    }
                }
            }
            __syncthreads();
            if (kh == 0) {
#pragma unroll
                for (int nn = 0; nn < 2; nn++) {
                    int n = nh * 2 + nn;
                    const char* base = lds + (((wr * 2 + wc) * 2 + nn) << 12) + lane * 64;
#pragma unroll
                    for (int q = 0; q < 4; q++) {
                        f32x4 v = *(const f32x4*)(base + ((q ^ (lane & 3)) << 4));
#pragma unroll
                        for (int e = 0; e < 4; e++) acc[m][n][q * 4 + e] += v[e];
                    }
                }
            }
            __syncthreads();
        }

    // -------- store (kh=0): C/D col=lane&31, row=(r&3)+8*(r>>2)+4*(lane>>5) --------
    if (kh == 0) {
#pragma unroll
        for (int m = 0; m < 2; m++) {
            int rbase = m0 + wr * 64 + m * 32 + ((lane >> 5) << 2);
#pragma unroll
            for (int n = 0; n < 4; n++) {
                int colg = n0 + wc * 128 + n * 32 + (lane & 31);
#pragma unroll
                for (int r = 0; r < 16; r++) {
                    int rowg = rbase + (r & 3) + 8 * (r >> 2);
                    out[(size_t)rowg * 1024 + colg] = acc[m][n][r];
                }
            }
        }
    }
}

extern "C" void kernel_launch(void* const* d_in, const int* in_sizes, int n_in,
                              void* d_out, int out_size, void* d_ws, size_t ws_size,
                              hipStream_t stream) {
    const float* x  = (const float*)d_in[0];
    const float* W  = (const float*)d_in[1];
    const float* sc = (const float*)d_in[2];
    const float* bi = (const float*)d_in[3];
    float* out = (float*)d_out;

    short* Wt2 = (short*)d_ws;
    float* b0  = (float*)((char*)d_ws + WS_B0_OFFSET);
    float* part = out;   // colsum partials staged in d_out (fully overwritten by gemm)

    hipLaunchKernelGGL(wt2_kernel, dim3(9 * 128), dim3(256), 0, stream, W, Wt2);
    hipLaunchKernelGGL(colsum1, dim3(128), dim3(256), 0, stream, W, part);
    hipLaunchKernelGGL(colsum2, dim3(4), dim3(256), 0, stream, part, b0);
    hipLaunchKernelGGL(cheby_gemm, dim3(256), dim3(512), 0, stream, x, Wt2, b0, sc, bi, out);
}

// Round 12
// 159.065 us; speedup vs baseline: 1.1425x; 1.1425x over previous
//
#include <hip/hip_runtime.h>
#include <hip/hip_bf16.h>

typedef __attribute__((ext_vector_type(8))) short short8;
typedef __attribute__((ext_vector_type(4))) float f32x4;
typedef __attribute__((ext_vector_type(16))) float f32x16;

#define WS_B0_OFFSET  18874368u   // b0 after Wt2 (9*1024*1024 bf16)

// -------- Phase 0a: W[d][i][o] fp32 -> Wt2[(d*128+q)][o][j] bf16 (i = q*8+j) --------
__global__ void wt2_kernel(const float* __restrict__ W, short* __restrict__ Wt2) {
    int bid = blockIdx.x;            // 0..1151
    int d = bid >> 7, q = bid & 127;
    int t = threadIdx.x;             // 256
    const float* src = W + (size_t)d * 1048576 + (size_t)q * 8 * 1024;
    short* dst = Wt2 + ((size_t)(d * 128 + q) << 13);
#pragma unroll
    for (int u = 0; u < 4; u++) {
        int o = u * 256 + t;
        short8 v;
#pragma unroll
        for (int j = 0; j < 8; j++)
            v[j] = (short)__bfloat16_as_ushort(__float2bfloat16(src[(size_t)j * 1024 + o]));
        *(short8*)(dst + (size_t)o * 8) = v;
    }
}

// -------- Phase 0b: b0[o] = sum_i W[0][i][o], two-stage --------
__global__ void colsum1(const float* __restrict__ W, float* __restrict__ part) {
    int s = blockIdx.x >> 2;
    int o = (blockIdx.x & 3) * 256 + threadIdx.x;
    const float* p = W + (size_t)s * 32 * 1024 + o;
    float acc = 0.f;
#pragma unroll
    for (int i = 0; i < 32; i++) acc += p[(size_t)i * 1024];
    part[s * 1024 + o] = acc;
}
__global__ void colsum2(const float* __restrict__ part, float* __restrict__ b0) {
    int o = blockIdx.x * 256 + threadIdx.x;
    float acc = 0.f;
#pragma unroll
    for (int s = 0; s < 32; s++) acc += part[s * 1024 + o];
    b0[o] = acc;
}

__device__ __forceinline__ float fast_tanh(float t) {
    float e = __expf(t + t);
    return 1.0f - 2.0f * __builtin_amdgcn_rcpf(e + 1.0f);
}

// -------- Phase 1: fused tanh + Chebyshev + GEMM --------
// R4 skeleton (tile 128x256, BK=32, grid 256 = 1 block/CU, barrier per step,
// B direct global->reg ping-pong one step ahead, A dbuf in LDS, kh-split
// accumulators). NEW vs R4: (1) wr-split waves (wr2 x wc2 x kh2; wave = 64
// rows x 128 cols x 16k) halve the per-step A-fragment LDS reads to 16 KB;
// (2) read-early ordering: readA -> bld -> recurrence+writeA -> burst ->
// drain+barrier, so recurrence VALU hides the ds_read latency.
extern "C" __global__ void __launch_bounds__(512, 2)
cheby_gemm(const float* __restrict__ x, const short* __restrict__ Wt2,
           const float* __restrict__ b0v, const float* __restrict__ scp,
           const float* __restrict__ bip, float* __restrict__ out) {
    __shared__ __align__(16) char lds[49152];   // A: 2x8KB @0; merge 32KB @16384

    const int tid = threadIdx.x, lane = tid & 63, wid = tid >> 6;
    const int wr = wid & 1, wc = (wid >> 1) & 1, kh = wid >> 2;
    const int tn = blockIdx.x & 3, tm = blockIdx.x >> 2;   // bid%8 -> fixed tn per XCD
    const int m0 = tm << 7, n0 = tn << 8;
    const float sc = scp[0], bi = bip[0];
    const char* wtb = (const char*)Wt2;

    // A ownership (write side): row = tid>>2, chunk ac = tid&3 (8 k-elems), dup-1
    const int arow = tid >> 2, ac = tid & 3;
    const int wbyte0 = ac * 2048 + ((arow ^ (ac << 1)) << 4);
    const float* xptr = x + (size_t)(m0 + arow) * 1024 + ac * 8;

    // A-frag read base: chunk cfr = kh*2 + (lane>>5); rows wr*64 + mm*32 + (lane&31)
    const int cfr = kh * 2 + (lane >> 5);
    const int abase = cfr * 2048 + (((lane & 31) ^ (cfr << 1)) << 4) + wr * 1024;
    // B byte offsets (4 n-blocks of the wave's 128 cols)
    int bofs[4];
#pragma unroll
    for (int n = 0; n < 4; n++)
        bofs[n] = (cfr << 14) + ((n0 + wc * 128 + n * 32 + (lane & 31)) << 4);

    auto bld = [&](short8* bf, int dd, int icc) {
        const char* p = wtb + ((size_t)(dd * 128 + icc * 4) << 14);
#pragma unroll
        for (int n = 0; n < 4; n++)
            bf[n] = *(const short8*)(p + bofs[n]);
    };

    f32x4 xv0, xv1;
    auto loadx = [&](int icc) {
        const float* p = xptr + (icc << 5);
        xv0 = *(const f32x4*)p;
        xv1 = *(const f32x4*)(p + 4);
    };

    float x2[8], tA[8], tB[8];
    auto dotanh = [&]() {
#pragma unroll
        for (int j = 0; j < 4; j++) {
            tA[j]     = fast_tanh(fmaf(xv0[j], sc, bi));
            tA[j + 4] = fast_tanh(fmaf(xv1[j], sc, bi));
        }
#pragma unroll
        for (int j = 0; j < 8; j++) x2[j] = tA[j] + tA[j];
    };
    auto writeA = [&](const float* t, int wbuf) {
        short8 v;
#pragma unroll
        for (int j = 0; j < 8; j++)
            v[j] = (short)__bfloat16_as_ushort(__float2bfloat16(t[j]));
        *(short8*)(lds + wbuf * 8192 + wbyte0) = v;
    };

    f32x16 acc[2][4];
#pragma unroll
    for (int n = 0; n < 4; n++) {
        float v = (kh == 0) ? b0v[n0 + wc * 128 + n * 32 + (lane & 31)] : 0.0f;
        f32x16 a;
#pragma unroll
        for (int r = 0; r < 16; r++) a[r] = v;
        acc[0][n] = a;
        acc[1][n] = a;
    }

    auto burst = [&](const short8* af, const short8* bf) {
        __builtin_amdgcn_s_setprio(1);
#pragma unroll
        for (int m = 0; m < 2; m++)
#pragma unroll
            for (int n = 0; n < 4; n++)
                acc[m][n] = __builtin_amdgcn_mfma_f32_32x32x16_bf16(af[m], bf[n], acc[m][n], 0, 0, 0);
        __builtin_amdgcn_s_setprio(0);
    };

    short8 bfs[2][4];

#define DRAIN_BAR                                                 \
    __builtin_amdgcn_sched_barrier(0);                            \
    asm volatile("s_waitcnt lgkmcnt(0)" ::: "memory");            \
    __builtin_amdgcn_s_barrier();                                 \
    __builtin_amdgcn_sched_barrier(0);

    // step s: readA(buf s&1) -> bld(slot (s+1)&1, d=s+2) -> recurrence+writeA
    //         (buf (s+1)&1) -> burst(af, slot s&1) -> drain+barrier
#define STEP(S, LD, LIC, RECUR, XPRE)                             \
    {                                                             \
        short8 af[2];                                             \
_Pragma("unroll")                                                 \
        for (int mm = 0; mm < 2; mm++)                            \
            af[mm] = *(const short8*)(lds + ((S) & 1) * 8192 + abase + mm * 512); \
        bld(bfs[((S) + 1) & 1], LD, LIC);                         \
        if (XPRE) loadx(icn);                                     \
        RECUR                                                     \
        burst(af, bfs[(S) & 1]);                                  \
        DRAIN_BAR                                                 \
    }
#define REC_T2   { for (int j = 0; j < 8; j++) tB[j] = fmaf(x2[j], tA[j], -1.0f);  writeA(tB, 1); }
#define REC_A(WB){ for (int j = 0; j < 8; j++) tA[j] = fmaf(x2[j], tB[j], -tA[j]); writeA(tA, WB); }
#define REC_B(WB){ for (int j = 0; j < 8; j++) tB[j] = fmaf(x2[j], tA[j], -tB[j]); writeA(tB, WB); }
#define REC_TANH { dotanh(); writeA(tA, 0); }

    // ---- prologue: x(0) -> T1 -> A-buf0; B(d=1) -> slot0 ----
    loadx(0);
    bld(bfs[0], 1, 0);
    dotanh();
    writeA(tA, 0);
    DRAIN_BAR

    for (int ic = 0; ic < 32; ++ic) {
        const int icn = ic < 31 ? ic + 1 : 31;
        STEP(0, 2, ic,  REC_T2,   0)   // d=1; make T2
        STEP(1, 3, ic,  REC_A(0), 0)   // d=2; make T3
        STEP(2, 4, ic,  REC_B(1), 0)   // d=3; make T4
        STEP(3, 5, ic,  REC_A(0), 0)   // d=4; make T5
        STEP(4, 6, ic,  REC_B(1), 0)   // d=5; make T6
        STEP(5, 7, ic,  REC_A(0), 1)   // d=6; make T7; prefetch x'
        STEP(6, 8, ic,  REC_B(1), 0)   // d=7; make T8
        STEP(7, 1, icn, REC_TANH, 0)   // d=8; make T1'
    }
#undef STEP
#undef REC_T2
#undef REC_A
#undef REC_B
#undef REC_TANH
#undef DRAIN_BAR

    // -------- kh-split merge (kh=1 added into kh=0), 4 chunks (mm x np) --------
#pragma unroll
    for (int mm = 0; mm < 2; mm++)
#pragma unroll
        for (int np = 0; np < 2; np++) {
            if (kh == 1) {
#pragma unroll
                for (int nn = 0; nn < 2; nn++) {
                    int n = np * 2 + nn;
                    char* base = lds + 16384 + (((wr * 2 + wc) * 2 + nn) << 12) + lane * 64;
#pragma unroll
                    for (int q = 0; q < 4; q++) {
                        f32x4 v = {acc[mm][n][q * 4 + 0], acc[mm][n][q * 4 + 1],
                                   acc[mm][n][q * 4 + 2], acc[mm][n][q * 4 + 3]};
                        *(f32x4*)(base + ((q ^ (lane & 3)) << 4)) = v;
                    }
                }
            }
            __syncthreads();
            if (kh == 0) {
#pragma unroll
                for (int nn = 0; nn < 2; nn++) {
                    int n = np * 2 + nn;
                    const char* base = lds + 16384 + (((wr * 2 + wc) * 2 + nn) << 12) + lane * 64;
#pragma unroll
                    for (int q = 0; q < 4; q++) {
                        f32x4 v = *(const f32x4*)(base + ((q ^ (lane & 3)) << 4));
#pragma unroll
                        for (int e = 0; e < 4; e++) acc[mm][n][q * 4 + e] += v[e];
                    }
                }
            }
            __syncthreads();
        }

    // -------- store (kh=0): C/D col=lane&31, row=(r&3)+8*(r>>2)+4*(lane>>5) --------
    if (kh == 0) {
#pragma unroll
        for (int mm = 0; mm < 2; mm++) {
            int rbase = m0 + wr * 64 + mm * 32 + ((lane >> 5) << 2);
#pragma unroll
            for (int n = 0; n < 4; n++) {
                int colg = n0 + wc * 128 + n * 32 + (lane & 31);
#pragma unroll
                for (int r = 0; r < 16; r++) {
                    int rowg = rbase + (r & 3) + 8 * (r >> 2);
                    out[(size_t)rowg * 1024 + colg] = acc[mm][n][r];
                }
            }
        }
    }
}

extern "C" void kernel_launch(void* const* d_in, const int* in_sizes, int n_in,
                              void* d_out, int out_size, void* d_ws, size_t ws_size,
                              hipStream_t stream) {
    const float* x  = (const float*)d_in[0];
    const float* W  = (const float*)d_in[1];
    const float* sc = (const float*)d_in[2];
    const float* bi = (const float*)d_in[3];
    float* out = (float*)d_out;

    short* Wt2 = (short*)d_ws;
    float* b0  = (float*)((char*)d_ws + WS_B0_OFFSET);
    float* part = out;   // colsum partials staged in d_out (fully overwritten by gemm)

    hipLaunchKernelGGL(wt2_kernel, dim3(9 * 128), dim3(256), 0, stream, W, Wt2);
    hipLaunchKernelGGL(colsum1, dim3(128), dim3(256), 0, stream, W, part);
    hipLaunchKernelGGL(colsum2, dim3(4), dim3(256), 0, stream, part, b0);
    hipLaunchKernelGGL(cheby_gemm, dim3(256), dim3(512), 0, stream, x, Wt2, b0, sc, bi, out);
}